// Round 2
// baseline (386.931 us; speedup 1.0000x reference)
//
#include <hip/hip_runtime.h>
#include <hip/hip_bf16.h>

// MoE SwiGLU MLP, sparse top-2 path.
// T=2048 tokens, D_MODEL=1024, D_FF=2048, E=8 experts, K=2.
// R5 baseline: 383.7us. rocprof: k_prep_w ~89us @ 2.24 TB/s (28% HBM) is the
//     top dispatch. Reads were 512B-segments at 8KB thread stride; writes 16B
//     scatter at 64B stride — per-instruction sparse on both sides.
// R6: k_prep_w rewritten as LDS-staged transpose: 4KB-contiguous-per-instr
//     reads -> bf16 linear LDS image -> b128 column reads + in-reg 8x8
//     transpose -> XOR-swizzled LDS chunk exchange -> 1KB-contiguous-per-wave
//     tiled writes. Same k-inner-8 output layout; GEMM kernels untouched.
//     Predict prep 90->~40us, total ~335us.

#define D_MODEL 1024
#define D_FF    2048
#define N_EXP   8
#define T_TOK   2048
#define MAXTILES 40   // sum_e ceil(cnt_e/128) <= 32+7 < 40

typedef __attribute__((ext_vector_type(8))) short bf16x8;
typedef __attribute__((ext_vector_type(8))) ushort u16x8;
typedef __attribute__((ext_vector_type(4))) float f32x4;

__device__ __forceinline__ ushort f2bf(float f) {
    union { float f; unsigned u; } c; c.f = f;
    unsigned u = c.u;
    return (ushort)((u + 0x7fffu + ((u >> 16) & 1u)) >> 16);  // RTNE
}

__device__ __forceinline__ void glds16(const void* g, void* l) {
    __builtin_amdgcn_global_load_lds(
        (const __attribute__((address_space(1))) unsigned int*)g,
        (__attribute__((address_space(3))) unsigned int*)l, 16, 0, 0);
}

// ---------------- weight prep: fp32 -> bf16, tiled k-inner-8 16KB blocks ----------------
// Output layout (unchanged): tile t*8192 ushorts; within tile [(kb*128+ncol)*8+ko],
// k = kt*64 + kb*8 + ko. Wg/Wu: t = e*256 + nt*16 + kt (N=2048,K=1024).
// Wd: t = e*256 + nt*32 + kt (N=1024,K=2048).
//
// Block = contiguous 64KB fp32 slab: Wg/Wu 8 rows x 2048; Wd 16 rows x 1024.
// Stage 1: 16x float4/thread, 4KB contiguous per instr, cvt, linear bf16 LDS.
// Stage 2: 8x ds_read_b128 (lane-contiguous) + in-register 8x8 u16 transpose.
//          Thread owns output chunks c = 8*tid+j (chunk = u16x8 = 8 ko of one col).
// Stage 3: swizzled LDS store  addr = c*16 ^ ((tid&7)<<4)  (bank-balanced),
//          barrier, re-read c = i*256+tid with same swizzle -> global store,
//          1KB contiguous per wave per instruction.
__global__ __launch_bounds__(256) void k_prep_w(
    const float* __restrict__ Wg, const float* __restrict__ Wu, const float* __restrict__ Wd,
    ushort* __restrict__ Wgt, ushort* __restrict__ Wut, ushort* __restrict__ Wdt)
{
    __shared__ __align__(16) ushort lds[16384];   // 32KB, reused in->out

    int s = blockIdx.x;          // 0..1023 slab index (128 per expert)
    int which = blockIdx.y;      // 0=Wg 1=Wu 2=Wd
    int tid = threadIdx.x;
    int e = s >> 7;

    const float* src; ushort* dst;
    int kt, kb, kbp;
    size_t soff;
    if (which == 2) {
        src = Wd; dst = Wdt;
        kt = (s >> 2) & 31; kbp = s & 3; kb = 0;
        soff = (size_t)e * 2048 * 1024 + (size_t)(kt * 64 + kbp * 16) * 1024;
    } else {
        src = which ? Wu : Wg; dst = which ? Wut : Wgt;
        kt = (s >> 3) & 15; kb = s & 7; kbp = 0;
        soff = (size_t)e * 1024 * 2048 + (size_t)(kt * 64 + kb * 8) * 2048;
    }
    const float4* p = (const float4*)(src + soff);

    // ---- stage 1: contiguous global read, cvt, linear LDS bf16 image ----
#pragma unroll
    for (int i = 0; i < 16; i++) {
        float4 v = p[i * 256 + tid];
        ushort4 o;
        o.x = f2bf(v.x); o.y = f2bf(v.y); o.z = f2bf(v.z); o.w = f2bf(v.w);
        *(ushort4*)&lds[(i * 256 + tid) * 4] = o;
    }
    __syncthreads();

    // ---- stage 2: read 8 rows x 8 cols, transpose in registers ----
    u16x8 in[8];
    if (which == 2) {
        int th = tid >> 7, tc = tid & 127;     // row-half, col-group
#pragma unroll
        for (int ko = 0; ko < 8; ko++)
            in[ko] = *(const u16x8*)&lds[(th * 8 + ko) * 1024 + tc * 8];
    } else {
#pragma unroll
        for (int ko = 0; ko < 8; ko++)
            in[ko] = *(const u16x8*)&lds[ko * 2048 + tid * 8];
    }
    u16x8 out[8];
#pragma unroll
    for (int j = 0; j < 8; j++)
#pragma unroll
        for (int ko = 0; ko < 8; ko++)
            out[j][ko] = in[ko][j];
    __syncthreads();

    // ---- stage 3: swizzled chunk exchange through LDS ----
    int swz = (tid & 7) << 4;
#pragma unroll
    for (int j = 0; j < 8; j++)
        *(u16x8*)((char*)lds + ((((8 * tid + j) * 16) ^ swz))) = out[j];
    __syncthreads();

#pragma unroll
    for (int i = 0; i < 8; i++) {
        int c = i * 256 + tid;
        u16x8 v = *(const u16x8*)((char*)lds + ((c * 16) ^ (((c >> 3) & 7) << 4)));
        int R = c >> 7, q = c & 127;
        size_t gaddr;
        if (which == 2) {
            int kb2 = R >> 3, ntp = R & 7;
            gaddr = (size_t)(e * 256 + ntp * 32 + kt) * 8192 + (kbp * 2 + kb2) * 1024 + q * 8;
        } else {
            gaddr = (size_t)(e * 256 + R * 16 + kt) * 8192 + kb * 1024 + q * 8;
        }
        *(u16x8*)&dst[gaddr] = v;
    }
}

// ---------------- router: 64 blocks x 32 tokens, block-aggregated atomics ----------------
// Also emits xb (bf16 copy of x) since it reads every x element anyway.
__global__ __launch_bounds__(256) void k_router(
    const float* __restrict__ x, const float* __restrict__ gw, const float* __restrict__ gb,
    int* cnt, float* probsum, int* tok, int* slotpk, float* wtok,
    ushort* __restrict__ xb)
{
    __shared__ float gws[N_EXP * D_MODEL];   // 32 KB
    __shared__ float ps_s[N_EXP];
    __shared__ int   bc_s[N_EXP];
    __shared__ int   gb_s[N_EXP];
    __shared__ int   a_e[64];                // 32 tokens x 2 assignments
    __shared__ int   a_lp[64];

    int tid = threadIdx.x;
    for (int i = tid; i < N_EXP * D_MODEL / 4; i += 256)
        ((float4*)gws)[i] = ((const float4*)gw)[i];
    if (tid < N_EXP) { ps_s[tid] = 0.f; bc_s[tid] = 0; }
    __syncthreads();

    int wave = tid >> 6, lane = tid & 63;

    for (int it = 0; it < 8; it++) {
        int tb = it * 4 + wave;                      // token-in-block
        int t = blockIdx.x * 32 + tb;
        const float4* xr = (const float4*)(x + (size_t)t * D_MODEL);
        ushort* xbr = xb + (size_t)t * D_MODEL;

        float acc[N_EXP];
#pragma unroll
        for (int e = 0; e < N_EXP; e++) acc[e] = 0.f;
#pragma unroll
        for (int q = 0; q < 4; q++) {
            int idx = q * 64 + lane;                 // coalesced + uniform banking
            float4 xv = xr[idx];
            ushort4 xc;
            xc.x = f2bf(xv.x); xc.y = f2bf(xv.y); xc.z = f2bf(xv.z); xc.w = f2bf(xv.w);
            *(ushort4*)&xbr[idx * 4] = xc;
#pragma unroll
            for (int e = 0; e < N_EXP; e++) {
                float4 gv = ((const float4*)(gws + e * D_MODEL))[idx];
                acc[e] += xv.x * gv.x + xv.y * gv.y + xv.z * gv.z + xv.w * gv.w;
            }
        }
#pragma unroll
        for (int off = 32; off > 0; off >>= 1) {
#pragma unroll
            for (int e = 0; e < N_EXP; e++) acc[e] += __shfl_xor(acc[e], off, 64);
        }
        if (lane == 0) {
            float l[N_EXP], m = -1e30f;
#pragma unroll
            for (int e = 0; e < N_EXP; e++) { l[e] = acc[e] + gb[e]; m = fmaxf(m, l[e]); }
            float p[N_EXP], s = 0.f;
#pragma unroll
            for (int e = 0; e < N_EXP; e++) { p[e] = expf(l[e] - m); s += p[e]; }
            float inv = 1.f / s;
#pragma unroll
            for (int e = 0; e < N_EXP; e++) { p[e] *= inv; atomicAdd(&ps_s[e], p[e]); }
            // top-2, lowest index wins ties (matches lax.top_k)
            int i0 = 0; float v0 = p[0];
#pragma unroll
            for (int e = 1; e < N_EXP; e++) if (p[e] > v0) { v0 = p[e]; i0 = e; }
            int i1 = -1; float v1 = -1.f;
#pragma unroll
            for (int e = 0; e < N_EXP; e++) if (e != i0 && p[e] > v1) { v1 = p[e]; i1 = e; }
            float winv = 1.f / (v0 + v1);
            int lp0 = atomicAdd(&bc_s[i0], 1);
            int lp1 = atomicAdd(&bc_s[i1], 1);
            a_e[tb * 2 + 0] = i0; a_lp[tb * 2 + 0] = lp0;
            a_e[tb * 2 + 1] = i1; a_lp[tb * 2 + 1] = lp1;
            wtok[t * 2 + 0] = v0 * winv;
            wtok[t * 2 + 1] = v1 * winv;
        }
    }
    __syncthreads();
    if (tid < N_EXP) {
        gb_s[tid] = atomicAdd(&cnt[tid], bc_s[tid]);
        atomicAdd(&probsum[tid], ps_s[tid]);
    }
    __syncthreads();
    if (tid < 64) {
        int tb = tid >> 1, k = tid & 1;
        int t = blockIdx.x * 32 + tb;
        int e = a_e[tid];
        int slot = gb_s[e] + a_lp[tid];
        tok[e * T_TOK + slot] = t;
        slotpk[t * 2 + k] = (e << 16) | slot;
    }
}

// ---------------- 128-aligned expert bases + tile table + balance loss ----------------
__global__ void k_base_loss(const int* __restrict__ cnt, const float* __restrict__ probsum,
                            int* abase, int* tile, float* loss_out)
{
    if (threadIdx.x == 0 && blockIdx.x == 0) {
        int b = 0, nt = 0;
        float loss = 0.f;
        for (int e = 0; e < N_EXP; e++) {
            abase[e] = b;
            for (int m0 = 0; m0 < cnt[e]; m0 += 128)
                tile[nt++] = (e << 16) | m0;
            b += ((cnt[e] + 127) >> 7) * 128;           // capacity-aligned
            float mean = probsum[e] * (1.0f / T_TOK);
            loss += 0.125f * (logf(0.125f) - logf(mean + 1e-9f));
        }
        for (; nt < MAXTILES; nt++) tile[nt] = -1;
        *loss_out = loss;
    }
}

// ---------------- stage A: h = silu(x@Wg + bg) * (x@Wu + bu) ----------------
// 128x128 tile, BK=64, 4 waves, dual accumulators. B via global_load_lds from
// pre-tiled weights; A gathered (tok) with uint4 copies; h written tiled.
__global__ __launch_bounds__(256, 2) void k_expert_gu(
    const ushort* __restrict__ Wgt, const ushort* __restrict__ Wut,
    const float* __restrict__ bg, const float* __restrict__ bu,
    const ushort* __restrict__ xb, const int* __restrict__ cnt,
    const int* __restrict__ abase, const int* __restrict__ tile,
    const int* __restrict__ tok, ushort* __restrict__ h_t)
{
    int ti = tile[blockIdx.x];
    if (ti < 0) return;                       // contiguous tail only
    int e = ti >> 16, m0 = ti & 0xffff;
    int ne = cnt[e];
    int nt = blockIdx.y;                      // 0..15
    int n0 = nt * 128;
    int stile = (abase[e] >> 7) + (m0 >> 7);  // global aligned slot-tile

    __shared__ __align__(16) ushort As[128 * 88];     // stride 88: 16B aligned, 2-way banks
    __shared__ __align__(16) ushort Bg_s[8192];       // k-inner-8 image (16KB)
    __shared__ __align__(16) ushort Bu_s[8192];

    int tid = threadIdx.x;
    int lane = tid & 63, wave = tid >> 6;
    int wm = (wave & 1) * 64, wn = (wave >> 1) * 64;

    // A staging: thread -> (row, k-half)
    int arow = tid >> 1;
    int akh = (tid & 1) * 32;
    int atok = tok[e * T_TOK + min(m0 + arow, ne - 1)];
    const ushort* xrow = xb + (size_t)atok * D_MODEL;

    // B tile bases (16KB per kt)
    const char* gbase = (const char*)(Wgt + (size_t)(e * 16 + nt) * 16 * 8192);
    const char* ubase = (const char*)(Wut + (size_t)(e * 16 + nt) * 16 * 8192);
    int goff = tid * 16;                      // per-lane global byte offset in tile
    int loff = (tid >> 6) * 1024;             // wave-uniform LDS byte offset

    f32x4 accg[4][4], accu[4][4];
#pragma unroll
    for (int i = 0; i < 4; i++)
#pragma unroll
        for (int j = 0; j < 4; j++) {
            accg[i][j] = (f32x4){0.f, 0.f, 0.f, 0.f};
            accu[i][j] = (f32x4){0.f, 0.f, 0.f, 0.f};
        }

    for (int kt = 0; kt < D_MODEL / 64; kt++) {
        __syncthreads();
        // A tile: bf16 gather copy, 16B chunks
#pragma unroll
        for (int q = 0; q < 4; q++)
            *(uint4*)&As[arow * 88 + akh + q * 8] = *(const uint4*)&xrow[kt * 64 + akh + q * 8];
        // B tiles: direct-to-LDS block copy (16KB each)
        const char* gsrc = gbase + kt * 16384;
        const char* usrc = ubase + kt * 16384;
#pragma unroll
        for (int q = 0; q < 4; q++) {
            glds16(gsrc + q * 4096 + goff, (char*)Bg_s + q * 4096 + loff);
            glds16(usrc + q * 4096 + goff, (char*)Bu_s + q * 4096 + loff);
        }
        __syncthreads();
        // compute
#pragma unroll
        for (int ks = 0; ks < 2; ks++) {
            bf16x8 af[4];
            int arow_f = wm + (lane & 15);
            int akb = ks * 32 + (lane >> 4) * 8;
#pragma unroll
            for (int sm = 0; sm < 4; sm++)
                af[sm] = *(const bf16x8*)&As[(arow_f + sm * 16) * 88 + akb];
            int bkb = ks * 4 + (lane >> 4);
#pragma unroll
            for (int sn = 0; sn < 4; sn++) {
                int ncol = wn + sn * 16 + (lane & 15);
                bf16x8 bgf = *(const bf16x8*)&Bg_s[(bkb * 128 + ncol) * 8];
                bf16x8 buf = *(const bf16x8*)&Bu_s[(bkb * 128 + ncol) * 8];
#pragma unroll
                for (int sm = 0; sm < 4; sm++) {
                    accg[sm][sn] = __builtin_amdgcn_mfma_f32_16x16x32_bf16(af[sm], bgf, accg[sm][sn], 0, 0, 0);
                    accu[sm][sn] = __builtin_amdgcn_mfma_f32_16x16x32_bf16(af[sm], buf, accu[sm][sn], 0, 0, 0);
                }
            }
        }
    }
    // epilogue: silu(g)*u -> h_t (bf16, tiled k-inner-8 for stage B's A-operand)
    int rbase = wm + ((lane >> 4) << 2);
    int cbase = wn + (lane & 15);
    size_t tbase = (size_t)stile * 32 * 8192;
#pragma unroll
    for (int sm = 0; sm < 4; sm++) {
#pragma unroll
        for (int r = 0; r < 4; r++) {
            int pos = m0 + rbase + sm * 16 + r;
            if (pos < ne) {
                int row = pos & 127;
#pragma unroll
                for (int sn = 0; sn < 4; sn++) {
                    int col = n0 + cbase + sn * 16;
                    float g = accg[sm][sn][r] + bg[e * D_FF + col];
                    float u = accu[sm][sn][r] + bu[e * D_FF + col];
                    float hv = (g / (1.f + expf(-g))) * u;
                    int ktb = col >> 6, kb = (col >> 3) & 7, ko = col & 7;
                    h_t[tbase + (size_t)ktb * 8192 + (kb * 128 + row) * 8 + ko] = f2bf(hv);
                }
            }
        }
    }
}

// ---------------- stage B: outp = h @ Wd + bd (both operands via global_load_lds) ----------------
__global__ __launch_bounds__(256, 2) void k_expert_down(
    const ushort* __restrict__ Wdt, const float* __restrict__ bd,
    const ushort* __restrict__ h_t, const int* __restrict__ cnt,
    const int* __restrict__ abase, const int* __restrict__ tile,
    float* __restrict__ outp)
{
    int ti = tile[blockIdx.x];
    if (ti < 0) return;
    int e = ti >> 16, m0 = ti & 0xffff;
    int ne = cnt[e];
    int nt = blockIdx.y;                      // 0..7
    int n0 = nt * 128;
    int stile = (abase[e] >> 7) + (m0 >> 7);

    __shared__ __align__(16) ushort As8[8192];        // k-inner-8 image (16KB)
    __shared__ __align__(16) ushort Bd_s[8192];

    int tid = threadIdx.x;
    int lane = tid & 63, wave = tid >> 6;
    int wm = (wave & 1) * 64, wn = (wave >> 1) * 64;

    const char* hbase = (const char*)(h_t + (size_t)stile * 32 * 8192);
    const char* dbase = (const char*)(Wdt + (size_t)(e * 8 + nt) * 32 * 8192);
    int goff = tid * 16;
    int loff = (tid >> 6) * 1024;

    f32x4 acc[4][4];
#pragma unroll
    for (int i = 0; i < 4; i++)
#pragma unroll
        for (int j = 0; j < 4; j++) acc[i][j] = (f32x4){0.f, 0.f, 0.f, 0.f};

    for (int kt = 0; kt < D_FF / 64; kt++) {
        __syncthreads();
        const char* asrc = hbase + kt * 16384;
        const char* bsrc = dbase + kt * 16384;
#pragma unroll
        for (int q = 0; q < 4; q++) {
            glds16(asrc + q * 4096 + goff, (char*)As8 + q * 4096 + loff);
            glds16(bsrc + q * 4096 + goff, (char*)Bd_s + q * 4096 + loff);
        }
        __syncthreads();
#pragma unroll
        for (int ks = 0; ks < 2; ks++) {
            bf16x8 af[4];
            int kb = ks * 4 + (lane >> 4);
            int arow_f = wm + (lane & 15);
#pragma unroll
            for (int sm = 0; sm < 4; sm++)
                af[sm] = *(const bf16x8*)&As8[(kb * 128 + arow_f + sm * 16) * 8];
#pragma unroll
            for (int sn = 0; sn < 4; sn++) {
                int ncol = wn + sn * 16 + (lane & 15);
                bf16x8 bdf = *(const bf16x8*)&Bd_s[(kb * 128 + ncol) * 8];
#pragma unroll
                for (int sm = 0; sm < 4; sm++)
                    acc[sm][sn] = __builtin_amdgcn_mfma_f32_16x16x32_bf16(af[sm], bdf, acc[sm][sn], 0, 0, 0);
            }
        }
    }
    int rbase = wm + ((lane >> 4) << 2);
    int cbase = wn + (lane & 15);
#pragma unroll
    for (int sm = 0; sm < 4; sm++) {
#pragma unroll
        for (int r = 0; r < 4; r++) {
            int pos = m0 + rbase + sm * 16 + r;
            if (pos < ne) {
                size_t ob = (size_t)(abase[e] + pos) * D_MODEL;
#pragma unroll
                for (int sn = 0; sn < 4; sn++) {
                    int col = n0 + cbase + sn * 16;
                    outp[ob + col] = acc[sm][sn][r] + bd[e * D_MODEL + col];
                }
            }
        }
    }
}

// ---------------- combine: y[t] = w0*outp[slot0] + w1*outp[slot1] ----------------
__global__ void k_combine(const float* __restrict__ outp, const int* __restrict__ slotpk,
                          const float* __restrict__ wtok, const int* __restrict__ abase,
                          float* __restrict__ y)
{
    int idx = blockIdx.x * 256 + threadIdx.x;   // 524288 float4s
    int t = idx >> 8, j = idx & 255;
    int sp0 = slotpk[t * 2 + 0], sp1 = slotpk[t * 2 + 1];
    float w0 = wtok[t * 2 + 0], w1 = wtok[t * 2 + 1];
    size_t s0 = (size_t)abase[sp0 >> 16] + (sp0 & 0xffff);
    size_t s1 = (size_t)abase[sp1 >> 16] + (sp1 & 0xffff);
    float4 a = ((const float4*)outp)[s0 * (D_MODEL / 4) + j];
    float4 b = ((const float4*)outp)[s1 * (D_MODEL / 4) + j];
    float4 o;
    o.x = w0 * a.x + w1 * b.x;
    o.y = w0 * a.y + w1 * b.y;
    o.z = w0 * a.z + w1 * b.z;
    o.w = w0 * a.w + w1 * b.w;
    ((float4*)y)[idx] = o;
}

extern "C" void kernel_launch(void* const* d_in, const int* in_sizes, int n_in,
                              void* d_out, int out_size, void* d_ws, size_t ws_size,
                              hipStream_t stream)
{
    const float* x  = (const float*)d_in[0];
    const float* gw = (const float*)d_in[1];
    const float* gb = (const float*)d_in[2];
    const float* Wg = (const float*)d_in[3];
    const float* bg = (const float*)d_in[4];
    const float* Wu = (const float*)d_in[5];
    const float* bu = (const float*)d_in[6];
    const float* Wd = (const float*)d_in[7];
    const float* bd = (const float*)d_in[8];
    float* y = (float*)d_out;
    float* loss_out = y + (size_t)T_TOK * D_MODEL;

    char* ws = (char*)d_ws;
    int*    cnt     = (int*)(ws + 0);             // 8 ints   [zeroed]  (own 128B line)
    float*  probsum = (float*)(ws + 128);         // 8 floats [zeroed]  (own 128B line)
    int*    abase   = (int*)(ws + 256);           // 8 ints (128-aligned bases)
    int*    tiletab = (int*)(ws + 320);           // MAXTILES ints
    int*    slotpk  = (int*)(ws + 512);           // 4096 ints
    float*  wtok    = (float*)(ws + 16896);       // 4096 floats
    int*    tok     = (int*)(ws + 33280);         // 8*2048 ints (ends 98816)
    ushort* xb      = (ushort*)(ws + 131072);     // 2M bf16 = 4 MB
    ushort* Wgt     = (ushort*)(ws + 4325376);    // 33.55 MB tiled bf16
    ushort* Wut     = (ushort*)(ws + 37879808);   // 33.55 MB
    ushort* Wdt     = (ushort*)(ws + 71434240);   // 33.55 MB
    ushort* h_t     = (ushort*)(ws + 104988672);  // 40 tiles * 32 kt * 16KB = 20.97 MB
    float*  outp    = (float*)(ws + 125960192);   // 5120*1024 fp32 = 20.97 MB
    // total ws use: ~140.1 MB

    hipMemsetAsync(d_ws, 0, 256, stream);
    k_prep_w<<<dim3(1024, 3), dim3(256), 0, stream>>>(Wg, Wu, Wd, Wgt, Wut, Wdt);
    k_router<<<dim3(64), dim3(256), 0, stream>>>(x, gw, gb, cnt, probsum, tok, slotpk, wtok, xb);
    k_base_loss<<<dim3(1), dim3(64), 0, stream>>>(cnt, probsum, abase, tiletab, loss_out);
    k_expert_gu<<<dim3(MAXTILES, 16), dim3(256), 0, stream>>>(Wgt, Wut, bg, bu, xb, cnt, abase, tiletab, tok, h_t);
    k_expert_down<<<dim3(MAXTILES, 8), dim3(256), 0, stream>>>(Wdt, bd, h_t, cnt, abase, tiletab, outp);
    k_combine<<<dim3(2048), dim3(256), 0, stream>>>(outp, slotpk, wtok, abase, y);
}

// Round 4
// 349.010 us; speedup vs baseline: 1.1087x; 1.1087x over previous
//
#include <hip/hip_runtime.h>
#include <hip/hip_bf16.h>

// MoE SwiGLU MLP, sparse top-2 path.
// T=2048 tokens, D_MODEL=1024, D_FF=2048, E=8 experts, K=2.
// R5 baseline 383.7us. R6 prep access-pattern rewrite: NO CHANGE (90us @ 2.23
//     TB/s both ways) — prep is memory-system-bound in situ, not pattern-bound.
// R7/R8: overlap instead of accelerate. Two block-role fusions of independent work:
//     (1) k_router_prep = router (64 blocks) + Wg/Wu prep (2048 blocks): the
//         latency-bound router hides under the prep stream.
//     (2) k_gu_prepwd = expert_gu (640 blocks, inner loop UNTOUCHED) + Wd prep
//         (1024 trailing blocks): prep-Wd's 100MB traffic overlaps gu stalls.
//     R8 = R7 with the dst_addr forward-reference compile error fixed (inlined).
//     Predict total 387 -> ~310-330us; gu counters become visible in top-5.

#define D_MODEL 1024
#define D_FF    2048
#define N_EXP   8
#define T_TOK   2048
#define MAXTILES 40   // sum_e ceil(cnt_e/128) <= 32+7 < 40

typedef __attribute__((ext_vector_type(8))) short bf16x8;
typedef __attribute__((ext_vector_type(8))) ushort u16x8;
typedef __attribute__((ext_vector_type(4))) float f32x4;

__device__ __forceinline__ ushort f2bf(float f) {
    union { float f; unsigned u; } c; c.f = f;
    unsigned u = c.u;
    return (ushort)((u + 0x7fffu + ((u >> 16) & 1u)) >> 16);  // RTNE
}

__device__ __forceinline__ void glds16(const void* g, void* l) {
    __builtin_amdgcn_global_load_lds(
        (const __attribute__((address_space(1))) unsigned int*)g,
        (__attribute__((address_space(3))) unsigned int*)l, 16, 0, 0);
}

// ---------------- prep helpers: fp32 -> bf16 tiled k-inner-8 (verified R6) ----------------
// Output layout: tile t*8192 ushorts; within tile [(kb*128+ncol)*8+ko],
// k = kt*64 + kb*8 + ko. Wg/Wu: t = e*256 + nt*16 + kt. Wd: t = e*256 + nt*32 + kt.
// Slab = contiguous 64KB fp32. Needs 32KB LDS scratch + 3 __syncthreads.
__device__ __forceinline__ void prep_slab_gwu(
    int sp, int tid, const float* __restrict__ Wg, const float* __restrict__ Wu,
    ushort* __restrict__ Wgt, ushort* __restrict__ Wut, ushort* lds)
{
    int which = sp >> 10, s = sp & 1023;
    const float* src = which ? Wu : Wg;
    ushort* dst = which ? Wut : Wgt;
    int e = s >> 7, kt = (s >> 3) & 15, kb = s & 7;
    const float4* p = (const float4*)(src + (size_t)e * 1024 * 2048 + (size_t)(kt * 64 + kb * 8) * 2048);
#pragma unroll
    for (int i = 0; i < 16; i++) {
        float4 v = p[i * 256 + tid];
        ushort4 o;
        o.x = f2bf(v.x); o.y = f2bf(v.y); o.z = f2bf(v.z); o.w = f2bf(v.w);
        *(ushort4*)&lds[(i * 256 + tid) * 4] = o;
    }
    __syncthreads();
    u16x8 in[8];
#pragma unroll
    for (int ko = 0; ko < 8; ko++)
        in[ko] = *(const u16x8*)&lds[ko * 2048 + tid * 8];
    u16x8 out[8];
#pragma unroll
    for (int j = 0; j < 8; j++)
#pragma unroll
        for (int ko = 0; ko < 8; ko++)
            out[j][ko] = in[ko][j];
    __syncthreads();
    int swz = (tid & 7) << 4;
#pragma unroll
    for (int j = 0; j < 8; j++)
        *(u16x8*)((char*)lds + (((8 * tid + j) * 16) ^ swz)) = out[j];
    __syncthreads();
#pragma unroll
    for (int i = 0; i < 8; i++) {
        int c = i * 256 + tid;
        u16x8 v = *(const u16x8*)((char*)lds + ((c * 16) ^ (((c >> 3) & 7) << 4)));
        int R = c >> 7, q = c & 127;
        *(u16x8*)&dst[(size_t)(e * 256 + R * 16 + kt) * 8192 + kb * 1024 + q * 8] = v;
    }
}

__device__ __forceinline__ void prep_slab_wd(
    int s, int tid, const float* __restrict__ Wd, ushort* __restrict__ Wdt, ushort* lds)
{
    int e = s >> 7, kt = (s >> 2) & 31, kbp = s & 3;
    const float4* p = (const float4*)(Wd + (size_t)e * 2048 * 1024 + (size_t)(kt * 64 + kbp * 16) * 1024);
#pragma unroll
    for (int i = 0; i < 16; i++) {
        float4 v = p[i * 256 + tid];
        ushort4 o;
        o.x = f2bf(v.x); o.y = f2bf(v.y); o.z = f2bf(v.z); o.w = f2bf(v.w);
        *(ushort4*)&lds[(i * 256 + tid) * 4] = o;
    }
    __syncthreads();
    u16x8 in[8];
    int th = tid >> 7, tc = tid & 127;
#pragma unroll
    for (int ko = 0; ko < 8; ko++)
        in[ko] = *(const u16x8*)&lds[(th * 8 + ko) * 1024 + tc * 8];
    u16x8 out[8];
#pragma unroll
    for (int j = 0; j < 8; j++)
#pragma unroll
        for (int ko = 0; ko < 8; ko++)
            out[j][ko] = in[ko][j];
    __syncthreads();
    int swz = (tid & 7) << 4;
#pragma unroll
    for (int j = 0; j < 8; j++)
        *(u16x8*)((char*)lds + (((8 * tid + j) * 16) ^ swz)) = out[j];
    __syncthreads();
#pragma unroll
    for (int i = 0; i < 8; i++) {
        int c = i * 256 + tid;
        u16x8 v = *(const u16x8*)((char*)lds + ((c * 16) ^ (((c >> 3) & 7) << 4)));
        int R = c >> 7, q = c & 127;
        int kb2 = R >> 3, ntp = R & 7;
        *(u16x8*)&Wdt[(size_t)(e * 256 + ntp * 32 + kt) * 8192 + (kbp * 2 + kb2) * 1024 + q * 8] = v;
    }
}

// ---------------- launch 1: router (blocks 0..63) + Wg/Wu prep (64..2111) ----------------
union SM1 {
    float gws[N_EXP * D_MODEL];   // 32 KB router gate-weight cache
    ushort prep[16384];           // 32 KB prep scratch
};

__global__ __launch_bounds__(256) void k_router_prep(
    const float* __restrict__ x, const float* __restrict__ gw, const float* __restrict__ gb,
    int* cnt, float* probsum, int* tok, int* slotpk, float* wtok,
    ushort* __restrict__ xb,
    const float* __restrict__ Wg, const float* __restrict__ Wu,
    ushort* __restrict__ Wgt, ushort* __restrict__ Wut)
{
    __shared__ __align__(16) SM1 sm;
    __shared__ float ps_s[N_EXP];
    __shared__ int   bc_s[N_EXP];
    __shared__ int   gb_s[N_EXP];
    __shared__ int   a_e[64];
    __shared__ int   a_lp[64];

    int tid = threadIdx.x;
    int bid = blockIdx.x;

    if (bid >= 64) {                      // ---- prep role ----
        prep_slab_gwu(bid - 64, tid, Wg, Wu, Wgt, Wut, sm.prep);
        return;
    }

    // ---- router role (verbatim from R5/R6) ----
    float* gws = sm.gws;
    for (int i = tid; i < N_EXP * D_MODEL / 4; i += 256)
        ((float4*)gws)[i] = ((const float4*)gw)[i];
    if (tid < N_EXP) { ps_s[tid] = 0.f; bc_s[tid] = 0; }
    __syncthreads();

    int wave = tid >> 6, lane = tid & 63;

    for (int it = 0; it < 8; it++) {
        int tb = it * 4 + wave;                      // token-in-block
        int t = bid * 32 + tb;
        const float4* xr = (const float4*)(x + (size_t)t * D_MODEL);
        ushort* xbr = xb + (size_t)t * D_MODEL;

        float acc[N_EXP];
#pragma unroll
        for (int e = 0; e < N_EXP; e++) acc[e] = 0.f;
#pragma unroll
        for (int q = 0; q < 4; q++) {
            int idx = q * 64 + lane;                 // coalesced + uniform banking
            float4 xv = xr[idx];
            ushort4 xc;
            xc.x = f2bf(xv.x); xc.y = f2bf(xv.y); xc.z = f2bf(xv.z); xc.w = f2bf(xv.w);
            *(ushort4*)&xbr[idx * 4] = xc;
#pragma unroll
            for (int e = 0; e < N_EXP; e++) {
                float4 gv = ((const float4*)(gws + e * D_MODEL))[idx];
                acc[e] += xv.x * gv.x + xv.y * gv.y + xv.z * gv.z + xv.w * gv.w;
            }
        }
#pragma unroll
        for (int off = 32; off > 0; off >>= 1) {
#pragma unroll
            for (int e = 0; e < N_EXP; e++) acc[e] += __shfl_xor(acc[e], off, 64);
        }
        if (lane == 0) {
            float l[N_EXP], m = -1e30f;
#pragma unroll
            for (int e = 0; e < N_EXP; e++) { l[e] = acc[e] + gb[e]; m = fmaxf(m, l[e]); }
            float p[N_EXP], s = 0.f;
#pragma unroll
            for (int e = 0; e < N_EXP; e++) { p[e] = expf(l[e] - m); s += p[e]; }
            float inv = 1.f / s;
#pragma unroll
            for (int e = 0; e < N_EXP; e++) { p[e] *= inv; atomicAdd(&ps_s[e], p[e]); }
            // top-2, lowest index wins ties (matches lax.top_k)
            int i0 = 0; float v0 = p[0];
#pragma unroll
            for (int e = 1; e < N_EXP; e++) if (p[e] > v0) { v0 = p[e]; i0 = e; }
            int i1 = -1; float v1 = -1.f;
#pragma unroll
            for (int e = 0; e < N_EXP; e++) if (e != i0 && p[e] > v1) { v1 = p[e]; i1 = e; }
            float winv = 1.f / (v0 + v1);
            int lp0 = atomicAdd(&bc_s[i0], 1);
            int lp1 = atomicAdd(&bc_s[i1], 1);
            a_e[tb * 2 + 0] = i0; a_lp[tb * 2 + 0] = lp0;
            a_e[tb * 2 + 1] = i1; a_lp[tb * 2 + 1] = lp1;
            wtok[t * 2 + 0] = v0 * winv;
            wtok[t * 2 + 1] = v1 * winv;
        }
    }
    __syncthreads();
    if (tid < N_EXP) {
        gb_s[tid] = atomicAdd(&cnt[tid], bc_s[tid]);
        atomicAdd(&probsum[tid], ps_s[tid]);
    }
    __syncthreads();
    if (tid < 64) {
        int tb = tid >> 1, k = tid & 1;
        int t = bid * 32 + tb;
        int e = a_e[tid];
        int slot = gb_s[e] + a_lp[tid];
        tok[e * T_TOK + slot] = t;
        slotpk[t * 2 + k] = (e << 16) | slot;
    }
}

// ---------------- 128-aligned expert bases + tile table + balance loss ----------------
__global__ void k_base_loss(const int* __restrict__ cnt, const float* __restrict__ probsum,
                            int* abase, int* tile, float* loss_out)
{
    if (threadIdx.x == 0 && blockIdx.x == 0) {
        int b = 0, nt = 0;
        float loss = 0.f;
        for (int e = 0; e < N_EXP; e++) {
            abase[e] = b;
            for (int m0 = 0; m0 < cnt[e]; m0 += 128)
                tile[nt++] = (e << 16) | m0;
            b += ((cnt[e] + 127) >> 7) * 128;           // capacity-aligned
            float mean = probsum[e] * (1.0f / T_TOK);
            loss += 0.125f * (logf(0.125f) - logf(mean + 1e-9f));
        }
        for (; nt < MAXTILES; nt++) tile[nt] = -1;
        *loss_out = loss;
    }
}

// ---------------- launch 3: stage A gu-GEMM (blocks 0..639) + Wd prep (640..1663) ----------------
struct SM_GU { ushort As[128 * 88]; ushort Bg[8192]; ushort Bu[8192]; };
union SM3 {
    SM_GU g;            // 54.5 KB gemm
    ushort prep[16384]; // 32 KB prep scratch
};

__global__ __launch_bounds__(256, 2) void k_gu_prepwd(
    const ushort* __restrict__ Wgt, const ushort* __restrict__ Wut,
    const float* __restrict__ bg, const float* __restrict__ bu,
    const ushort* __restrict__ xb, const int* __restrict__ cnt,
    const int* __restrict__ abase, const int* __restrict__ tile,
    const int* __restrict__ tok, ushort* __restrict__ h_t,
    const float* __restrict__ Wd, ushort* __restrict__ Wdt)
{
    __shared__ __align__(16) SM3 sm;

    int bid = blockIdx.x;
    int tid = threadIdx.x;

    if (bid >= MAXTILES * 16) {           // ---- prep-Wd role ----
        prep_slab_wd(bid - MAXTILES * 16, tid, Wd, Wdt, sm.prep);
        return;
    }

    // ---- gu GEMM role (inner loop identical to R5/R6) ----
    int ti = tile[bid % MAXTILES];
    if (ti < 0) return;                       // contiguous tail only
    int e = ti >> 16, m0 = ti & 0xffff;
    int ne = cnt[e];
    int nt = bid / MAXTILES;                  // 0..15
    int n0 = nt * 128;
    int stile = (abase[e] >> 7) + (m0 >> 7);  // global aligned slot-tile

    ushort* As = sm.g.As;
    ushort* Bg_s = sm.g.Bg;
    ushort* Bu_s = sm.g.Bu;

    int lane = tid & 63, wave = tid >> 6;
    int wm = (wave & 1) * 64, wn = (wave >> 1) * 64;

    // A staging: thread -> (row, k-half)
    int arow = tid >> 1;
    int akh = (tid & 1) * 32;
    int atok = tok[e * T_TOK + min(m0 + arow, ne - 1)];
    const ushort* xrow = xb + (size_t)atok * D_MODEL;

    // B tile bases (16KB per kt)
    const char* gbase = (const char*)(Wgt + (size_t)(e * 16 + nt) * 16 * 8192);
    const char* ubase = (const char*)(Wut + (size_t)(e * 16 + nt) * 16 * 8192);
    int goff = tid * 16;                      // per-lane global byte offset in tile
    int loff = (tid >> 6) * 1024;             // wave-uniform LDS byte offset

    f32x4 accg[4][4], accu[4][4];
#pragma unroll
    for (int i = 0; i < 4; i++)
#pragma unroll
        for (int j = 0; j < 4; j++) {
            accg[i][j] = (f32x4){0.f, 0.f, 0.f, 0.f};
            accu[i][j] = (f32x4){0.f, 0.f, 0.f, 0.f};
        }

    for (int kt = 0; kt < D_MODEL / 64; kt++) {
        __syncthreads();
        // A tile: bf16 gather copy, 16B chunks
#pragma unroll
        for (int q = 0; q < 4; q++)
            *(uint4*)&As[arow * 88 + akh + q * 8] = *(const uint4*)&xrow[kt * 64 + akh + q * 8];
        // B tiles: direct-to-LDS block copy (16KB each)
        const char* gsrc = gbase + kt * 16384;
        const char* usrc = ubase + kt * 16384;
#pragma unroll
        for (int q = 0; q < 4; q++) {
            glds16(gsrc + q * 4096 + goff, (char*)Bg_s + q * 4096 + loff);
            glds16(usrc + q * 4096 + goff, (char*)Bu_s + q * 4096 + loff);
        }
        __syncthreads();
        // compute
#pragma unroll
        for (int ks = 0; ks < 2; ks++) {
            bf16x8 af[4];
            int arow_f = wm + (lane & 15);
            int akb = ks * 32 + (lane >> 4) * 8;
#pragma unroll
            for (int sm_ = 0; sm_ < 4; sm_++)
                af[sm_] = *(const bf16x8*)&As[(arow_f + sm_ * 16) * 88 + akb];
            int bkb = ks * 4 + (lane >> 4);
#pragma unroll
            for (int sn = 0; sn < 4; sn++) {
                int ncol = wn + sn * 16 + (lane & 15);
                bf16x8 bgf = *(const bf16x8*)&Bg_s[(bkb * 128 + ncol) * 8];
                bf16x8 buf = *(const bf16x8*)&Bu_s[(bkb * 128 + ncol) * 8];
#pragma unroll
                for (int sm_ = 0; sm_ < 4; sm_++) {
                    accg[sm_][sn] = __builtin_amdgcn_mfma_f32_16x16x32_bf16(af[sm_], bgf, accg[sm_][sn], 0, 0, 0);
                    accu[sm_][sn] = __builtin_amdgcn_mfma_f32_16x16x32_bf16(af[sm_], buf, accu[sm_][sn], 0, 0, 0);
                }
            }
        }
    }
    // epilogue: silu(g)*u -> h_t (bf16, tiled k-inner-8 for stage B's A-operand)
    int rbase = wm + ((lane >> 4) << 2);
    int cbase = wn + (lane & 15);
    size_t tbase = (size_t)stile * 32 * 8192;
#pragma unroll
    for (int sm_ = 0; sm_ < 4; sm_++) {
#pragma unroll
        for (int r = 0; r < 4; r++) {
            int pos = m0 + rbase + sm_ * 16 + r;
            if (pos < ne) {
                int row = pos & 127;
#pragma unroll
                for (int sn = 0; sn < 4; sn++) {
                    int col = n0 + cbase + sn * 16;
                    float g = accg[sm_][sn][r] + bg[e * D_FF + col];
                    float u = accu[sm_][sn][r] + bu[e * D_FF + col];
                    float hv = (g / (1.f + expf(-g))) * u;
                    int ktb = col >> 6, kb = (col >> 3) & 7, ko = col & 7;
                    h_t[tbase + (size_t)ktb * 8192 + (kb * 128 + row) * 8 + ko] = f2bf(hv);
                }
            }
        }
    }
}

// ---------------- stage B: outp = h @ Wd + bd (both operands via global_load_lds) ----------------
__global__ __launch_bounds__(256, 2) void k_expert_down(
    const ushort* __restrict__ Wdt, const float* __restrict__ bd,
    const ushort* __restrict__ h_t, const int* __restrict__ cnt,
    const int* __restrict__ abase, const int* __restrict__ tile,
    float* __restrict__ outp)
{
    int ti = tile[blockIdx.x];
    if (ti < 0) return;
    int e = ti >> 16, m0 = ti & 0xffff;
    int ne = cnt[e];
    int nt = blockIdx.y;                      // 0..7
    int n0 = nt * 128;
    int stile = (abase[e] >> 7) + (m0 >> 7);

    __shared__ __align__(16) ushort As8[8192];        // k-inner-8 image (16KB)
    __shared__ __align__(16) ushort Bd_s[8192];

    int tid = threadIdx.x;
    int lane = tid & 63, wave = tid >> 6;
    int wm = (wave & 1) * 64, wn = (wave >> 1) * 64;

    const char* hbase = (const char*)(h_t + (size_t)stile * 32 * 8192);
    const char* dbase = (const char*)(Wdt + (size_t)(e * 8 + nt) * 32 * 8192);
    int goff = tid * 16;
    int loff = (tid >> 6) * 1024;

    f32x4 acc[4][4];
#pragma unroll
    for (int i = 0; i < 4; i++)
#pragma unroll
        for (int j = 0; j < 4; j++) acc[i][j] = (f32x4){0.f, 0.f, 0.f, 0.f};

    for (int kt = 0; kt < D_FF / 64; kt++) {
        __syncthreads();
        const char* asrc = hbase + kt * 16384;
        const char* bsrc = dbase + kt * 16384;
#pragma unroll
        for (int q = 0; q < 4; q++) {
            glds16(asrc + q * 4096 + goff, (char*)As8 + q * 4096 + loff);
            glds16(bsrc + q * 4096 + goff, (char*)Bd_s + q * 4096 + loff);
        }
        __syncthreads();
#pragma unroll
        for (int ks = 0; ks < 2; ks++) {
            bf16x8 af[4];
            int kb = ks * 4 + (lane >> 4);
            int arow_f = wm + (lane & 15);
#pragma unroll
            for (int sm_ = 0; sm_ < 4; sm_++)
                af[sm_] = *(const bf16x8*)&As8[(kb * 128 + arow_f + sm_ * 16) * 8];
#pragma unroll
            for (int sn = 0; sn < 4; sn++) {
                int ncol = wn + sn * 16 + (lane & 15);
                bf16x8 bdf = *(const bf16x8*)&Bd_s[(kb * 128 + ncol) * 8];
#pragma unroll
                for (int sm_ = 0; sm_ < 4; sm_++)
                    acc[sm_][sn] = __builtin_amdgcn_mfma_f32_16x16x32_bf16(af[sm_], bdf, acc[sm_][sn], 0, 0, 0);
            }
        }
    }
    int rbase = wm + ((lane >> 4) << 2);
    int cbase = wn + (lane & 15);
#pragma unroll
    for (int sm_ = 0; sm_ < 4; sm_++) {
#pragma unroll
        for (int r = 0; r < 4; r++) {
            int pos = m0 + rbase + sm_ * 16 + r;
            if (pos < ne) {
                size_t ob = (size_t)(abase[e] + pos) * D_MODEL;
#pragma unroll
                for (int sn = 0; sn < 4; sn++) {
                    int col = n0 + cbase + sn * 16;
                    outp[ob + col] = acc[sm_][sn][r] + bd[e * D_MODEL + col];
                }
            }
        }
    }
}

// ---------------- combine: y[t] = w0*outp[slot0] + w1*outp[slot1] ----------------
__global__ void k_combine(const float* __restrict__ outp, const int* __restrict__ slotpk,
                          const float* __restrict__ wtok, const int* __restrict__ abase,
                          float* __restrict__ y)
{
    int idx = blockIdx.x * 256 + threadIdx.x;   // 524288 float4s
    int t = idx >> 8, j = idx & 255;
    int sp0 = slotpk[t * 2 + 0], sp1 = slotpk[t * 2 + 1];
    float w0 = wtok[t * 2 + 0], w1 = wtok[t * 2 + 1];
    size_t s0 = (size_t)abase[sp0 >> 16] + (sp0 & 0xffff);
    size_t s1 = (size_t)abase[sp1 >> 16] + (sp1 & 0xffff);
    float4 a = ((const float4*)outp)[s0 * (D_MODEL / 4) + j];
    float4 b = ((const float4*)outp)[s1 * (D_MODEL / 4) + j];
    float4 o;
    o.x = w0 * a.x + w1 * b.x;
    o.y = w0 * a.y + w1 * b.y;
    o.z = w0 * a.z + w1 * b.z;
    o.w = w0 * a.w + w1 * b.w;
    ((float4*)y)[idx] = o;
}

extern "C" void kernel_launch(void* const* d_in, const int* in_sizes, int n_in,
                              void* d_out, int out_size, void* d_ws, size_t ws_size,
                              hipStream_t stream)
{
    const float* x  = (const float*)d_in[0];
    const float* gw = (const float*)d_in[1];
    const float* gb = (const float*)d_in[2];
    const float* Wg = (const float*)d_in[3];
    const float* bg = (const float*)d_in[4];
    const float* Wu = (const float*)d_in[5];
    const float* bu = (const float*)d_in[6];
    const float* Wd = (const float*)d_in[7];
    const float* bd = (const float*)d_in[8];
    float* y = (float*)d_out;
    float* loss_out = y + (size_t)T_TOK * D_MODEL;

    char* ws = (char*)d_ws;
    int*    cnt     = (int*)(ws + 0);             // 8 ints   [zeroed]  (own 128B line)
    float*  probsum = (float*)(ws + 128);         // 8 floats [zeroed]  (own 128B line)
    int*    abase   = (int*)(ws + 256);           // 8 ints (128-aligned bases)
    int*    tiletab = (int*)(ws + 320);           // MAXTILES ints
    int*    slotpk  = (int*)(ws + 512);           // 4096 ints
    float*  wtok    = (float*)(ws + 16896);       // 4096 floats
    int*    tok     = (int*)(ws + 33280);         // 8*2048 ints (ends 98816)
    ushort* xb      = (ushort*)(ws + 131072);     // 2M bf16 = 4 MB
    ushort* Wgt     = (ushort*)(ws + 4325376);    // 33.55 MB tiled bf16
    ushort* Wut     = (ushort*)(ws + 37879808);   // 33.55 MB
    ushort* Wdt     = (ushort*)(ws + 71434240);   // 33.55 MB
    ushort* h_t     = (ushort*)(ws + 104988672);  // 40 tiles * 32 kt * 16KB = 20.97 MB
    float*  outp    = (float*)(ws + 125960192);   // 5120*1024 fp32 = 20.97 MB
    // total ws use: ~140.1 MB

    (void)hipMemsetAsync(d_ws, 0, 256, stream);
    // launch 1: router (64 blocks) overlapped with Wg/Wu prep (2048 blocks)
    k_router_prep<<<dim3(64 + 2048), dim3(256), 0, stream>>>(
        x, gw, gb, cnt, probsum, tok, slotpk, wtok, xb, Wg, Wu, Wgt, Wut);
    k_base_loss<<<dim3(1), dim3(64), 0, stream>>>(cnt, probsum, abase, tiletab, loss_out);
    // launch 3: gu GEMM (640 blocks) overlapped with Wd prep (1024 blocks)
    k_gu_prepwd<<<dim3(MAXTILES * 16 + 1024), dim3(256), 0, stream>>>(
        Wgt, Wut, bg, bu, xb, cnt, abase, tiletab, tok, h_t, Wd, Wdt);
    k_expert_down<<<dim3(MAXTILES, 8), dim3(256), 0, stream>>>(Wdt, bd, h_t, cnt, abase, tiletab, outp);
    k_combine<<<dim3(2048), dim3(256), 0, stream>>>(outp, slotpk, wtok, abase, y);
}